// Round 4
// baseline (632.639 us; speedup 1.0000x reference)
//
#include <hip/hip_runtime.h>
#include <hip/hip_bf16.h>

#define EDGES   640000
#define NNODES  50000
#define MDIM    128
#define HDIM    64
#define XSTR    36    // padded LDS stride (floats) for f32 staging kernels

typedef __attribute__((ext_vector_type(8))) short bshort8;  // 8 bf16 = 4 VGPRs
typedef __attribute__((ext_vector_type(4))) float f32x4;    // MFMA acc

__device__ __forceinline__ short f2bf(float f) {
    __hip_bfloat16 h = __float2bfloat16(f);
    return *reinterpret_cast<short*>(&h);
}

// exact-gelu via Abramowitz-Stegun 7.1.26 erf approx (|err| < 1.5e-7)
__device__ __forceinline__ float gelu_fast(float h) {
    const float x  = h * 0.70710678118654752f;
    const float ax = fabsf(x);
    const float t  = __builtin_amdgcn_rcpf(fmaf(0.3275911f, ax, 1.0f));
    float p = fmaf(1.061405429f, t, -1.453152027f);
    p = fmaf(p, t,  1.421413741f);
    p = fmaf(p, t, -0.284496736f);
    p = fmaf(p, t,  0.254829592f);
    p *= t;
    const float e = __expf(-x * x);
    float er = fmaf(-p, e, 1.0f);
    er = (x < 0.0f) ? -er : er;
    return 0.5f * h * (1.0f + er);
}

// ---------------- K0: pack W1 message-half into bf16 MFMA B-fragment layout (bpack),
// hidden-unit permutation j = 4*n + jt (so g/w2 reads in k1 are ONE float4 per lane),
// and W1 feature-half transposed f32 (w1dt) for kg_nodes.
__global__ void k0_prep(const float* __restrict__ w1,
                        short* __restrict__ bpack, float* __restrict__ w1dt) {
    const int i = blockIdx.x * 256 + threadIdx.x;   // 0..16383
    if (i < 8192) {
        const int ii   = i & 7;
        const int lane = (i >> 3) & 63;
        const int jtkc = i >> 9;            // kc*4 + jt
        const int kc = jtkc >> 2, jt = jtkc & 3;
        const int j = 4 * (lane & 15) + jt;             // permuted hidden unit
        const int k = kc * 32 + (lane >> 4) * 8 + ii;
        bpack[i] = f2bf(w1[j * 256 + k]);
    } else if (i < 16384) {
        const int t = i - 8192;             // w1dt[k][j] = W1[j][128+k]
        const int k = t >> 6, j = t & 63;
        w1dt[t] = w1[j * 256 + 128 + k];
    }
}

// ---------------- KG: g[n][j] = b1[j] + sum_k feats[n][k]*W1d[j][k]  (f32 FMA, lane-per-node)
__global__ __launch_bounds__(256, 4) void kg_nodes(
    const float* __restrict__ feats, const float* __restrict__ w1dt,
    const float* __restrict__ b1, float* __restrict__ g)
{
    __shared__ float xs[4][64 * XSTR];
    const int wv = threadIdx.x >> 6, L = threadIdx.x & 63;
    const long base = ((long)blockIdx.x * 4 + wv) * 64;
    float* xb = xs[wv];
    float h[HDIM];
#pragma unroll
    for (int j = 0; j < HDIM; ++j) h[j] = 0.0f;
    const int gq = L >> 3, sub = L & 7;
    for (int c = 0; c < 4; ++c) {
        const int col0 = c * 32;
#pragma unroll
        for (int r = 0; r < 8; ++r) {
            long row = base + gq + 8 * r;
            if (row > NNODES - 1) row = NNODES - 1;
            float4 v = *(const float4*)(feats + row * MDIM + col0 + sub * 4);
            *(float4*)(xb + (gq + 8 * r) * XSTR + sub * 4) = v;
        }
        __syncthreads();
        for (int k4 = 0; k4 < 8; ++k4) {
            const float4 xv = *(const float4*)(xb + L * XSTR + 4 * k4);
            const float* colw = w1dt + (c * 32 + 4 * k4) * HDIM;
            const float xa[4] = {xv.x, xv.y, xv.z, xv.w};
#pragma unroll
            for (int kk = 0; kk < 4; ++kk) {
                const float xk = xa[kk];
#pragma unroll
                for (int j = 0; j < HDIM; ++j)
                    h[j] = fmaf(colw[kk * HDIM + j], xk, h[j]);
            }
        }
        __syncthreads();
    }
    const long row = base + L;
    if (row < NNODES) {
        float* gp = g + row * HDIM;
#pragma unroll
        for (int j4 = 0; j4 < 16; ++j4) {
            float4 b4 = *(const float4*)(b1 + 4 * j4);
            float4 o;
            o.x = h[4 * j4 + 0] + b4.x; o.y = h[4 * j4 + 1] + b4.y;
            o.z = h[4 * j4 + 2] + b4.z; o.w = h[4 * j4 + 3] + b4.w;
            *(float4*)(gp + 4 * j4) = o;
        }
    }
}

// ---------------- K1: streaming edge MLP, NO LDS / NO barrier.
// Wave handles 16 dense edges; lane (n,quad) loads row base+n's quad-segments
// directly (its exact MFMA A-frag data), f2bf in-register, 16 MFMAs.
// Hidden unit of (n,jt) = 4n+jt  ->  g-row read is ONE float4 per edge, w2 one float4.
__global__ __launch_bounds__(256) void k1_weights(
    const float* __restrict__ msgs, const int* __restrict__ tgt,
    const short* __restrict__ bpack, const float* __restrict__ g,
    const float* __restrict__ w2, float* __restrict__ weights,
    int* __restrict__ counts)
{
    const int wv = threadIdx.x >> 6, L = threadIdx.x & 63;
    const long base = ((long)blockIdx.x * 4 + wv) * 16;
    const int n = L & 15, quad = L >> 4;
    const bshort8* bp = (const bshort8*)bpack;

    // dense row base+n, this quad's 8-float segment of each 32-col chunk
    const float* rp = msgs + (base + n) * MDIM + quad * 8;
    float4 v[8];
#pragma unroll
    for (int kc = 0; kc < 4; ++kc) {
        v[2 * kc]     = *(const float4*)(rp + kc * 32);
        v[2 * kc + 1] = *(const float4*)(rp + kc * 32 + 4);
    }

    const float4 w2v = *(const float4*)(w2 + 4 * n);

    f32x4 hacc[4];
#pragma unroll
    for (int jt = 0; jt < 4; ++jt) hacc[jt] = (f32x4){0.f, 0.f, 0.f, 0.f};
#pragma unroll
    for (int kc = 0; kc < 4; ++kc) {
        const float4 va = v[2 * kc], vb = v[2 * kc + 1];
        bshort8 a;
        a[0] = f2bf(va.x); a[1] = f2bf(va.y); a[2] = f2bf(va.z); a[3] = f2bf(va.w);
        a[4] = f2bf(vb.x); a[5] = f2bf(vb.y); a[6] = f2bf(vb.z); a[7] = f2bf(vb.w);
#pragma unroll
        for (int jt = 0; jt < 4; ++jt)
            hacc[jt] = __builtin_amdgcn_mfma_f32_16x16x32_bf16(a, bp[(kc * 4 + jt) * 64 + L], hacc[jt], 0, 0, 0);
    }

    // epilogue: lane holds h[edge = quad*4+r][hidden 4n+jt]
#pragma unroll
    for (int r = 0; r < 4; ++r) {
        const long e = base + quad * 4 + r;
        const int t = tgt[e];
        const float4 g4 = *(const float4*)(g + (long)t * HDIM + 4 * n);
        float raw;
        {
            const float h0 = hacc[0][r] + g4.x;
            const float h1 = hacc[1][r] + g4.y;
            const float h2 = hacc[2][r] + g4.z;
            const float h3 = hacc[3][r] + g4.w;
            raw = gelu_fast(h0) * w2v.x;
            raw = fmaf(gelu_fast(h1), w2v.y, raw);
            raw = fmaf(gelu_fast(h2), w2v.z, raw);
            raw = fmaf(gelu_fast(h3), w2v.w, raw);
        }
#pragma unroll
        for (int off = 1; off < 16; off <<= 1)
            raw += __shfl_xor(raw, off, 64);
        if (n == r) {
            weights[e] = 1.0f / (1.0f + __expf(-raw));
            atomicAdd(&counts[t], 1);
        }
    }
}

// ---------------- CSR build
__global__ void kscan_local(const int* __restrict__ counts, int* __restrict__ offsets,
                            int* __restrict__ blocksums) {
    __shared__ int s[256];
    const int tid = threadIdx.x;
    const int i = blockIdx.x * 256 + tid;
    int v = (i < NNODES) ? counts[i] : 0;
    s[tid] = v;
    __syncthreads();
    for (int d = 1; d < 256; d <<= 1) {
        int t = (tid >= d) ? s[tid - d] : 0;
        __syncthreads();
        s[tid] += t;
        __syncthreads();
    }
    if (i < NNODES) offsets[i] = s[tid];
    if (tid == 255) blocksums[blockIdx.x] = s[255];
}

__global__ void kscan_blk(int* __restrict__ blocksums, int nblk) {
    __shared__ int s[256];
    const int tid = threadIdx.x;
    int v = (tid < nblk) ? blocksums[tid] : 0;
    s[tid] = v;
    __syncthreads();
    for (int d = 1; d < 256; d <<= 1) {
        int t = (tid >= d) ? s[tid - d] : 0;
        __syncthreads();
        s[tid] += t;
        __syncthreads();
    }
    if (tid < nblk) blocksums[tid] = s[tid] - v;
}

__global__ void kscan_fix(int* __restrict__ offsets, const int* __restrict__ blocksums,
                          const int* __restrict__ counts, int* __restrict__ cursor) {
    const int i = blockIdx.x * 256 + threadIdx.x;
    if (i < NNODES) {
        const int incl = offsets[i] + blocksums[i >> 8];
        offsets[i] = incl;
        cursor[i] = incl - counts[i];
    }
}

__global__ void kscatter(const int* __restrict__ tgt, int* __restrict__ cursor,
                         int* __restrict__ eidx) {
    const int e = blockIdx.x * 256 + threadIdx.x;
    if (e < EDGES) {
        const int pos = atomicAdd(&cursor[tgt[e]], 1);
        eidx[pos] = e;
    }
}

// ---------------- K_AGG: wave-per-node, 8 row-groups x 8 lanes.
// Per iteration the wave pulls 8 msg rows; each lane owns cols [lg*16, lg*16+16)
// of its group's row => 4 INDEPENDENT float4 loads in flight per lane (4 KB/wave/iter).
// End-of-node: 3-round reduce-scatter across groups (lane ends with 2 unique cols),
// fused divide + LayerNorm, float2 store.
__global__ __launch_bounds__(256) void kagg(
    const float* __restrict__ msgs, const float* __restrict__ wts,
    const int* __restrict__ eidx, const int* __restrict__ offsets,
    const float* __restrict__ gamma, const float* __restrict__ beta,
    float* __restrict__ out)
{
    const int L = threadIdx.x & 63, wv = threadIdx.x >> 6;
    const int node = blockIdx.x * 4 + wv;
    if (node >= NNODES) return;
    const int end = offsets[node];
    const int beg = (node == 0) ? 0 : offsets[node - 1];
    const int m = end - beg;

    const int gr = L >> 3;          // row-group 0..7
    const int lg = L & 7;           // cols [lg*16, lg*16+16)
    float4 a0 = {0.f,0.f,0.f,0.f}, a1 = a0, a2 = a0, a3 = a0;
    float swl = 0.0f;

    for (int b = 0; b < m; b += 64) {
        int mm = m - b; if (mm > 64) mm = 64;
        int eid = 0; float w = 0.0f;
        if (L < mm) { eid = eidx[beg + b + L]; w = wts[eid]; }
        swl += w;                                   // each slot counted exactly once
        const int nit = (mm + 7) >> 3;
        for (int i = 0; i < nit; ++i) {
            const int slot = i * 8 + gr;
            const int   er = __shfl(eid, slot, 64); // pads: eid=0 row (broadcast), w=0
            const float wr = __shfl(w,   slot, 64);
            const float* rp = msgs + (long)er * MDIM + lg * 16;
            const float4 v0 = *(const float4*)(rp);
            const float4 v1 = *(const float4*)(rp + 4);
            const float4 v2 = *(const float4*)(rp + 8);
            const float4 v3 = *(const float4*)(rp + 12);
            a0.x = fmaf(v0.x, wr, a0.x); a0.y = fmaf(v0.y, wr, a0.y);
            a0.z = fmaf(v0.z, wr, a0.z); a0.w = fmaf(v0.w, wr, a0.w);
            a1.x = fmaf(v1.x, wr, a1.x); a1.y = fmaf(v1.y, wr, a1.y);
            a1.z = fmaf(v1.z, wr, a1.z); a1.w = fmaf(v1.w, wr, a1.w);
            a2.x = fmaf(v2.x, wr, a2.x); a2.y = fmaf(v2.y, wr, a2.y);
            a2.z = fmaf(v2.z, wr, a2.z); a2.w = fmaf(v2.w, wr, a2.w);
            a3.x = fmaf(v3.x, wr, a3.x); a3.y = fmaf(v3.y, wr, a3.y);
            a3.z = fmaf(v3.z, wr, a3.z); a3.w = fmaf(v3.w, wr, a3.w);
        }
    }

    // reduce-scatter across the 8 row-groups.
    // round 1 (xor 8): keep 8 floats; cols += (gr&1)*8
    {
        const float4 k0 = (gr & 1) ? a2 : a0;
        const float4 k1 = (gr & 1) ? a3 : a1;
        const float4 s0 = (gr & 1) ? a0 : a2;
        const float4 s1 = (gr & 1) ? a1 : a3;
        a0.x = k0.x + __shfl_xor(s0.x, 8, 64);
        a0.y = k0.y + __shfl_xor(s0.y, 8, 64);
        a0.z = k0.z + __shfl_xor(s0.z, 8, 64);
        a0.w = k0.w + __shfl_xor(s0.w, 8, 64);
        a1.x = k1.x + __shfl_xor(s1.x, 8, 64);
        a1.y = k1.y + __shfl_xor(s1.y, 8, 64);
        a1.z = k1.z + __shfl_xor(s1.z, 8, 64);
        a1.w = k1.w + __shfl_xor(s1.w, 8, 64);
    }
    // round 2 (xor 16): keep 4 floats; cols += (gr&2)*2... (+4 if gr&2)
    {
        const float4 k0 = (gr & 2) ? a1 : a0;
        const float4 s0 = (gr & 2) ? a0 : a1;
        a0.x = k0.x + __shfl_xor(s0.x, 16, 64);
        a0.y = k0.y + __shfl_xor(s0.y, 16, 64);
        a0.z = k0.z + __shfl_xor(s0.z, 16, 64);
        a0.w = k0.w + __shfl_xor(s0.w, 16, 64);
    }
    // round 3 (xor 32): keep 2 floats; cols += (gr&4)?2:0
    float S0, S1;
    {
        const float kx = (gr & 4) ? a0.z : a0.x;
        const float ky = (gr & 4) ? a0.w : a0.y;
        const float sx = (gr & 4) ? a0.x : a0.z;
        const float sy = (gr & 4) ? a0.y : a0.w;
        S0 = kx + __shfl_xor(sx, 32, 64);
        S1 = ky + __shfl_xor(sy, 32, 64);
    }
    // this lane's two unique cols
    const int col = lg * 16 + (gr & 1) * 8 + ((gr & 2) << 1) + ((gr & 4) >> 1);

    // full-wave reductions (cols unique per lane now)
    float s1 = S0 + S1;
    float s2 = S0 * S0 + S1 * S1;
#pragma unroll
    for (int off = 32; off; off >>= 1) {
        s1 += __shfl_xor(s1, off, 64);
        s2 += __shfl_xor(s2, off, 64);
        swl += __shfl_xor(swl, off, 64);
    }

    const float inv = 1.0f / (swl + 1e-8f);
    const float a0v = S0 * inv, a1v = S1 * inv;
    const float mu = s1 * inv * (1.0f / MDIM);
    const float var = s2 * inv * inv * (1.0f / MDIM) - mu * mu;
    const float rs = rsqrtf(var + 1e-5f);
    const float2 gm = *(const float2*)(gamma + col);
    const float2 bt = *(const float2*)(beta + col);
    float2 o;
    o.x = (a0v - mu) * rs * gm.x + bt.x;
    o.y = (a1v - mu) * rs * gm.y + bt.y;
    *(float2*)(out + (long)node * MDIM + col) = o;
}

extern "C" void kernel_launch(void* const* d_in, const int* in_sizes, int n_in,
                              void* d_out, int out_size, void* d_ws, size_t ws_size,
                              hipStream_t stream) {
    const float* msgs  = (const float*)d_in[0];
    const int*   tgt   = (const int*)d_in[1];
    const float* feats = (const float*)d_in[2];
    const float* W1    = (const float*)d_in[4];
    const float* b1    = (const float*)d_in[5];
    const float* W2    = (const float*)d_in[6];
    const float* gamma = (const float*)d_in[7];
    const float* beta  = (const float*)d_in[8];
    float* out = (float*)d_out;

    char* ws = (char*)d_ws;
    short* bpack   = (short*)(ws + 0);                 //  16 KB
    float* w1dt    = (float*)(ws + (32 << 10));        //  32 KB
    int*   counts  = (int*)  (ws + (64 << 10));        // 200 KB
    int*   offsets = (int*)  (ws + (320 << 10));       // 200 KB
    int*   cursor  = (int*)  (ws + (576 << 10));       // 200 KB
    int*   bsums   = (int*)  (ws + (832 << 10));       //   1 KB
    float* wts     = (float*)(ws + (1 << 20));         // 2.56 MB
    int*   eidx    = (int*)  (ws + (4 << 20));         // 2.56 MB
    float* g       = (float*)(ws + (8 << 20));         // 12.8 MB

    hipMemsetAsync(counts, 0, NNODES * sizeof(int), stream);

    k0_prep<<<64, 256, 0, stream>>>(W1, bpack, w1dt);
    kg_nodes<<<(NNODES + 255) / 256, 256, 0, stream>>>(feats, w1dt, b1, g);
    k1_weights<<<EDGES / 64, 256, 0, stream>>>(msgs, tgt, bpack, g, W2, wts, counts);
    const int nblk = (NNODES + 255) / 256;
    kscan_local<<<nblk, 256, 0, stream>>>(counts, offsets, bsums);
    kscan_blk<<<1, 256, 0, stream>>>(bsums, nblk);
    kscan_fix<<<nblk, 256, 0, stream>>>(offsets, bsums, counts, cursor);
    kscatter<<<(EDGES + 255) / 256, 256, 0, stream>>>(tgt, cursor, eidx);
    kagg<<<(NNODES + 3) / 4, 256, 0, stream>>>(msgs, wts, eidx, offsets, gamma, beta, out);
}